// Round 8
// baseline (222.676 us; speedup 1.0000x reference)
//
#include <hip/hip_runtime.h>

#define NB 64
#define SS 512
#define HIDD 256
#define NHEADS 4
#define ADIM 64
#define NTOT 576   // Wq(256) + Wk(256) + Wv(64) concatenated output cols

typedef __attribute__((ext_vector_type(8))) short short8v;
typedef __attribute__((ext_vector_type(4))) float f32x4;

#define MFMA16(A, B, C) __builtin_amdgcn_mfma_f32_16x16x32_bf16(A, B, C, 0, 0, 0)
#define AS1 __attribute__((address_space(1)))
#define AS3 __attribute__((address_space(3)))

// async 16B/lane global->LDS copy (dest = wave-uniform base + lane*16)
__device__ __forceinline__ void g2l16(void* lds, const void* g) {
    __builtin_amdgcn_global_load_lds((const AS1 unsigned*)g,
                                     (AS3 unsigned*)lds, 16, 0, 0);
}

// split fp32 x into bf16 hi + bf16 lo with x ~= hi + lo (error ~2^-17 rel)
__device__ __forceinline__ void bsplit(float x, short& hi, short& lo) {
    unsigned u = __float_as_uint(x);
    unsigned uh = (u + 0x8000u) & 0xFFFF0000u;
    hi = (short)(uh >> 16);
    float r = x - __uint_as_float(uh);
    lo = (short)((__float_as_uint(r) + 0x8000u) >> 16);
}

__device__ __forceinline__ void bsplit_v(float x, short8v& vh, short8v& vl, int i) {
    short h, l;
    bsplit(x, h, l);
    vh[i] = h;
    vl[i] = l;
}

// fragment-tiled Q/K address: [b][h][t16][ks2][lane][8], lane = rk + 16*lgk
__device__ __forceinline__ int frag_addr(int bb, int hh, int s, int d) {
    const int t16 = s >> 4, rk = s & 15;
    const int ks2 = d >> 5, lgk = (d >> 3) & 3, e8 = d & 7;
    return ((((bb * 4 + hh) * 32 + t16) * 2 + ks2) * 64 + rk + 16 * lgk) * 8 + e8;
}

// ---------------------------------------------------------------------------
// Pre-split + transpose weights: WT[n][k], n in [0,576): {Wq | Wk | Wv}
// ---------------------------------------------------------------------------
__global__ __launch_bounds__(256) void prep_weights(
    const float* __restrict__ Wq, const float* __restrict__ Wk,
    const float* __restrict__ Wv, short* __restrict__ WT_hi,
    short* __restrict__ WT_lo)
{
    const int idx = blockIdx.x * 256 + threadIdx.x;   // 576*256 elements
    const int n = idx >> 8, k = idx & 255;
    float v;
    if (n < 256)      v = Wq[k * 256 + n];
    else if (n < 512) v = Wk[k * 256 + (n - 256)];
    else              v = Wv[k * 64 + (n - 512)];
    short h, l;
    bsplit(v, h, l);
    WT_hi[idx] = h;
    WT_lo[idx] = l;
}

// ---------------------------------------------------------------------------
// Fused Q/K/V projection GEMM (MFMA split-bf16, 3-term), LDS-staged.
// 1-D grid 2304, XCD-grouped swizzle: the 9 nb-blocks of one m-tile run
// consecutively on the same XCD -> A rows fetched once, L2-served after.
// ---------------------------------------------------------------------------
__global__ __launch_bounds__(256) void qkv_gemm(
    const float* __restrict__ query, const float* __restrict__ key,
    const float* __restrict__ value,
    const short* __restrict__ WT_hi, const short* __restrict__ WT_lo,
    const float* __restrict__ bq, const float* __restrict__ bk,
    const float* __restrict__ bv,
    short* __restrict__ Qhi, short* __restrict__ Qlo,
    short* __restrict__ Khi, short* __restrict__ Klo,
    float* __restrict__ V)
{
    __shared__ float Af[2][128 * 32];     // 16 KB per buffer
    __shared__ short Wh_s[2][64 * 32];    // 4 KB per buffer
    __shared__ short Wl_s[2][64 * 32];    // 4 KB per buffer

    // bijective XCD-grouping swizzle: xcd gets m-tiles [xcd*32, xcd*32+32),
    // nb iterates innermost within an XCD's slot sequence.
    const int d = blockIdx.x;             // 0..2303
    const int xcd = d & 7;
    const int slot = d >> 3;              // 0..287
    const int mt = xcd * 32 + slot / 9;   // 0..255
    const int nb = slot % 9;

    const int bm = mt * 128;
    const int bn = nb * 64;
    const int tid = threadIdx.x;
    const int w = tid >> 6;
    const int l = tid & 63;
    const int l15 = l & 15, lg = l >> 4;
    const int wbase = tid & 192;          // w*64, wave-uniform

    const float* A = (nb < 4) ? query : (nb < 8) ? key : value;

    f32x4 acc[2][4];
#pragma unroll
    for (int mf = 0; mf < 2; ++mf)
#pragma unroll
        for (int j = 0; j < 4; ++j) acc[mf][j] = (f32x4){0.f, 0.f, 0.f, 0.f};

    // ---- staging: A chunk [128][32] f32, WT chunk [64][32] hi+lo ----
    auto stage = [&](int buf, int kc) {
        const int k0 = kc * 32;
#pragma unroll
        for (int i = 0; i < 4; ++i) {
            const int g = i * 256 + tid;          // 16B-slot id, 0..1023
            const int row = g >> 3;               // 0..127
            const int p = g & 7;                  // physical 16B slot in row
            const int sl = p ^ (row & 7);         // logical slot (source)
            g2l16(&Af[buf][(i * 256 + wbase) * 4],
                  A + (size_t)(bm + row) * HIDD + k0 + sl * 4);
        }
        {
            const int row = tid >> 2;             // 0..63
            const int p = tid & 3;
            const int sl = p ^ (row & 3);
            const size_t goff = (size_t)(bn + row) * HIDD + k0 + sl * 8;
            g2l16(&Wh_s[buf][wbase * 8], WT_hi + goff);
            g2l16(&Wl_s[buf][wbase * 8], WT_lo + goff);
        }
    };

    stage(0, 0);
    __syncthreads();   // compiler drains vmcnt(0) before s_barrier

    int cur = 0;
#pragma unroll
    for (int kc = 0; kc < 8; ++kc) {
        if (kc < 7) stage(cur ^ 1, kc + 1);   // prefetch overlaps compute

        // ---- A fragments from LDS (swizzled) + bsplit ----
        short8v ah[2], al[2];
#pragma unroll
        for (int mf = 0; mf < 2; ++mf) {
            const int rowA = w * 32 + mf * 16 + l15;
            const int s0 = (lg * 2 + 0) ^ (rowA & 7);
            const int s1 = (lg * 2 + 1) ^ (rowA & 7);
            float4 a0 = *reinterpret_cast<const float4*>(&Af[cur][rowA * 32 + s0 * 4]);
            float4 a1 = *reinterpret_cast<const float4*>(&Af[cur][rowA * 32 + s1 * 4]);
            bsplit_v(a0.x, ah[mf], al[mf], 0);
            bsplit_v(a0.y, ah[mf], al[mf], 1);
            bsplit_v(a0.z, ah[mf], al[mf], 2);
            bsplit_v(a0.w, ah[mf], al[mf], 3);
            bsplit_v(a1.x, ah[mf], al[mf], 4);
            bsplit_v(a1.y, ah[mf], al[mf], 5);
            bsplit_v(a1.z, ah[mf], al[mf], 6);
            bsplit_v(a1.w, ah[mf], al[mf], 7);
        }

        // ---- WT fragments + MFMA (3-term split) ----
#pragma unroll
        for (int j = 0; j < 4; ++j) {
            const int rowB = j * 16 + l15;
            const int sl = lg ^ (rowB & 3);
            short8v bh = *reinterpret_cast<const short8v*>(&Wh_s[cur][rowB * 32 + sl * 8]);
            short8v bl = *reinterpret_cast<const short8v*>(&Wl_s[cur][rowB * 32 + sl * 8]);
#pragma unroll
            for (int mf = 0; mf < 2; ++mf) {
                acc[mf][j] = MFMA16(ah[mf], bh, acc[mf][j]);
                acc[mf][j] = MFMA16(ah[mf], bl, acc[mf][j]);
                acc[mf][j] = MFMA16(al[mf], bh, acc[mf][j]);
            }
        }
        __syncthreads();   // waves done reading `cur`; prefetch landed
        cur ^= 1;
    }

    // ---- epilogue: bias + fragment-tiled split-store (Q/K) or fp32 (V) ----
    const float* biasp = (nb < 4) ? bq : (nb < 8) ? bk : bv;
    const int nloc_base = (nb < 4) ? bn : (nb < 8) ? bn - 256 : 0;
#pragma unroll
    for (int mf = 0; mf < 2; ++mf)
#pragma unroll
        for (int j = 0; j < 4; ++j) {
            const int ncol = nloc_base + j * 16 + l15;
            const float bias = biasp[ncol];
            if (nb < 8) {
                short* Dhi = (nb < 4) ? Qhi : Khi;
                short* Dlo = (nb < 4) ? Qlo : Klo;
#pragma unroll
                for (int r = 0; r < 4; ++r) {
                    const int m = bm + w * 32 + mf * 16 + lg * 4 + r;
                    const int bb = m >> 9, s = m & 511;
                    const int hh = ncol >> 6, dd = ncol & 63;
                    const int fa = frag_addr(bb, hh, s, dd);
                    short h, lo_;
                    bsplit(acc[mf][j][r] + bias, h, lo_);
                    Dhi[fa] = h;
                    Dlo[fa] = lo_;
                }
            } else {
#pragma unroll
                for (int r = 0; r < 4; ++r) {
                    const int m = bm + w * 32 + mf * 16 + lg * 4 + r;
                    V[(size_t)m * ADIM + ncol] = acc[mf][j][r] + bias;
                }
            }
        }
}

// ---------------------------------------------------------------------------
// attn[b,q,k] = mean_h softmax_k( mask ? (Q_h . K_h)/8 : -inf )
// MFMA split-bf16. K tiles (contiguous 16KB frag-slabs) are DMA-staged to
// LDS via global_load_lds, double-buffered, one barrier per tile (T3 2-phase).
// Q staged single-buffered one head ahead. No row-max (shift-invariant).
// ---------------------------------------------------------------------------
__global__ __launch_bounds__(256) void attn_probs_mfma(
    const short* __restrict__ Qhi_g, const short* __restrict__ Qlo_g,
    const short* __restrict__ Khi_g, const short* __restrict__ Klo_g,
    const int* __restrict__ mask, float* __restrict__ attn)
{
    __shared__ short Kh_s[2][8192];   // [buf][tt(8)][ks2(2)][lane(64)][8]  16KB
    __shared__ short Kl_s[2][8192];
    __shared__ short Qh_s[2048];      // [qs(2)][ks2(2)][lane(64)][8]       4KB
    __shared__ short Ql_s[2048];
    __shared__ float red[2][4][2][16];

    // bijective XCD swizzle: 1024 blocks = 8 xcds x 128
    const int wg = blockIdx.x;
    const int swz = (wg & 7) * 128 + (wg >> 3);
    const int b = swz >> 4;
    const int q0 = (swz & 15) * 32;
    const int qt_base = (swz & 15) * 2;   // q-tile16 index base

    const int tid = threadIdx.x;
    const int w = tid >> 6;          // wave 0..3 -> k-subtiles {2w, 2w+1} per 128-tile
    const int l = tid & 63;
    const int l15 = l & 15;
    const int lg = l >> 4;

    // ---- staging helpers (frag-tiled slabs are contiguous) ----
    auto stageK = [&](int buf, int h, int kt) {
        const int tb = ((b * 4 + h) * 32 + kt * 8) * 1024;   // shorts
        const short* sh = Khi_g + tb;
        const short* sl = Klo_g + tb;
#pragma unroll
        for (int i = 0; i < 4; ++i) {
            const int seg = i * 4 + w;                       // wave-uniform
            g2l16(&Kh_s[buf][seg * 512], sh + seg * 512 + l * 8);
            g2l16(&Kl_s[buf][seg * 512], sl + seg * 512 + l * 8);
        }
    };
    auto stageQ = [&](int h) {
        const int tb = ((b * 4 + h) * 32 + qt_base) * 1024;  // shorts
        g2l16(&Qh_s[w * 512], Qhi_g + tb + w * 512 + l * 8);
        g2l16(&Ql_s[w * 512], Qlo_g + tb + w * 512 + l * 8);
    };

    // ---- pack mask bits: per lane, per qs: 8 frags x 4 k-bits ----
    unsigned mbits[2];
#pragma unroll
    for (int qs = 0; qs < 2; ++qs) {
        unsigned bits = 0;
        const int q = q0 + qs * 16 + l15;
        const int* mrow = mask + ((size_t)b * SS + q) * SS;
#pragma unroll
        for (int f = 0; f < 8; ++f) {
            const int kt = f >> 1, ms = f & 1;
            const int k = kt * 128 + (2 * w + ms) * 16 + lg * 4;
            int4 mv = *reinterpret_cast<const int4*>(&mrow[k]);
            bits |= (mv.x != 0 ? 1u : 0u) << (f * 4 + 0);
            bits |= (mv.y != 0 ? 1u : 0u) << (f * 4 + 1);
            bits |= (mv.z != 0 ? 1u : 0u) << (f * 4 + 2);
            bits |= (mv.w != 0 ? 1u : 0u) << (f * 4 + 3);
        }
        mbits[qs] = bits;
    }

    f32x4 acc[4][2][2];
#pragma unroll
    for (int kt = 0; kt < 4; ++kt)
#pragma unroll
        for (int ms = 0; ms < 2; ++ms)
#pragma unroll
            for (int qs = 0; qs < 2; ++qs)
                acc[kt][ms][qs] = (f32x4){0.f, 0.f, 0.f, 0.f};

    // ---- prologue: stage first K tile + head-0 Q ----
    stageK(0, 0, 0);
    stageQ(0);
    __syncthreads();   // vmcnt(0) drain + barrier

    short8v qh[2][2], ql[2][2];

#pragma unroll
    for (int h = 0; h < NHEADS; ++h) {
        f32x4 e[4][2][2];
#pragma unroll
        for (int kt = 0; kt < 4; ++kt)
#pragma unroll
            for (int ms = 0; ms < 2; ++ms)
#pragma unroll
                for (int qs = 0; qs < 2; ++qs)
                    e[kt][ms][qs] = (f32x4){0.f, 0.f, 0.f, 0.f};

#pragma unroll
        for (int kt = 0; kt < 4; ++kt) {
            const int t = h * 4 + kt;
            const int buf = t & 1;

            // prefetch next tile / next head's Q (overlaps this tile's compute)
            if (t < 15) stageK(buf ^ 1, (t + 1) >> 2, (t + 1) & 3);
            if (kt == 1 && h < 3) stageQ(h + 1);

            // head start: pull Q fragments LDS -> regs (reused over 4 kt)
            if (kt == 0) {
#pragma unroll
                for (int ks2 = 0; ks2 < 2; ++ks2)
#pragma unroll
                    for (int qs = 0; qs < 2; ++qs) {
                        const int off = (qs * 2 + ks2) * 512 + l * 8;
                        qh[ks2][qs] = *reinterpret_cast<const short8v*>(&Qh_s[off]);
                        ql[ks2][qs] = *reinterpret_cast<const short8v*>(&Ql_s[off]);
                    }
            }

            // ---- K fragments from LDS + MFMA (3-term split) ----
#pragma unroll
            for (int ks2 = 0; ks2 < 2; ++ks2) {
                const int o0 = ((2 * w + 0) * 2 + ks2) * 512 + l * 8;
                const int o1 = ((2 * w + 1) * 2 + ks2) * 512 + l * 8;
                short8v ah0 = *reinterpret_cast<const short8v*>(&Kh_s[buf][o0]);
                short8v ah1 = *reinterpret_cast<const short8v*>(&Kh_s[buf][o1]);
                short8v al0 = *reinterpret_cast<const short8v*>(&Kl_s[buf][o0]);
                short8v al1 = *reinterpret_cast<const short8v*>(&Kl_s[buf][o1]);

                e[kt][0][0] = MFMA16(ah0, qh[ks2][0], e[kt][0][0]);
                e[kt][0][0] = MFMA16(ah0, ql[ks2][0], e[kt][0][0]);
                e[kt][0][0] = MFMA16(al0, qh[ks2][0], e[kt][0][0]);

                e[kt][0][1] = MFMA16(ah0, qh[ks2][1], e[kt][0][1]);
                e[kt][0][1] = MFMA16(ah0, ql[ks2][1], e[kt][0][1]);
                e[kt][0][1] = MFMA16(al0, qh[ks2][1], e[kt][0][1]);

                e[kt][1][0] = MFMA16(ah1, qh[ks2][0], e[kt][1][0]);
                e[kt][1][0] = MFMA16(ah1, ql[ks2][0], e[kt][1][0]);
                e[kt][1][0] = MFMA16(al1, qh[ks2][0], e[kt][1][0]);

                e[kt][1][1] = MFMA16(ah1, qh[ks2][1], e[kt][1][1]);
                e[kt][1][1] = MFMA16(ah1, ql[ks2][1], e[kt][1][1]);
                e[kt][1][1] = MFMA16(al1, qh[ks2][1], e[kt][1][1]);
            }

            // head end: masked exp (no max shift) + sum + head-mean accumulate
            if (kt == 3) {
                float sm[2] = {0.f, 0.f};
                const float c = 0.125f;
#pragma unroll
                for (int k2 = 0; k2 < 4; ++k2)
#pragma unroll
                    for (int ms = 0; ms < 2; ++ms)
#pragma unroll
                        for (int qs = 0; qs < 2; ++qs)
#pragma unroll
                            for (int r = 0; r < 4; ++r) {
                                float p = __expf(e[k2][ms][qs][r] * c);
                                const unsigned bit =
                                    (mbits[qs] >> ((k2 * 2 + ms) * 4 + r)) & 1u;
                                p = bit ? p : 0.f;
                                e[k2][ms][qs][r] = p;
                                sm[qs] += p;
                            }
#pragma unroll
                for (int qs = 0; qs < 2; ++qs) {
                    sm[qs] += __shfl_xor(sm[qs], 16);
                    sm[qs] += __shfl_xor(sm[qs], 32);
                }
                if (l < 16) { red[h & 1][w][0][l] = sm[0]; red[h & 1][w][1][l] = sm[1]; }
                __syncthreads();
#pragma unroll
                for (int qs = 0; qs < 2; ++qs) {
                    const float Z = (red[h & 1][0][qs][l15] + red[h & 1][1][qs][l15]) +
                                    (red[h & 1][2][qs][l15] + red[h & 1][3][qs][l15]);
                    const float inv = 0.25f / fmaxf(Z, 1e-30f);
#pragma unroll
                    for (int k2 = 0; k2 < 4; ++k2)
#pragma unroll
                        for (int ms = 0; ms < 2; ++ms)
#pragma unroll
                            for (int r = 0; r < 4; ++r)
                                acc[k2][ms][qs][r] += e[k2][ms][qs][r] * inv;
                }
            }

            __syncthreads();   // end of tile: drains prefetch, protects buffers
        }
    }

    // ---- write attention tile ----
#pragma unroll
    for (int kt = 0; kt < 4; ++kt)
#pragma unroll
        for (int ms = 0; ms < 2; ++ms)
#pragma unroll
            for (int qs = 0; qs < 2; ++qs) {
                const int q = q0 + qs * 16 + l15;
                const int k = kt * 128 + (2 * w + ms) * 16 + lg * 4;
                float4 o;
                o.x = acc[kt][ms][qs][0];
                o.y = acc[kt][ms][qs][1];
                o.z = acc[kt][ms][qs][2];
                o.w = acc[kt][ms][qs][3];
                *reinterpret_cast<float4*>(&attn[((size_t)b * SS + q) * SS + k]) = o;
            }
}

// ---------------------------------------------------------------------------
// B2: out[b,q,:] = (attention[b,q,:] @ V[b]) @ Wh + bh
// ---------------------------------------------------------------------------
__global__ __launch_bounds__(256) void attn_out_kernel(
    const float* __restrict__ attn, const float* __restrict__ V,
    const float* __restrict__ Wh, const float* __restrict__ bh,
    float* __restrict__ out)
{
    __shared__ float UsT[64][68];
    __shared__ float R[64 * 68 * 2];
    float* AsT = R;
    float* Vs  = R + 64 * 68;
    float* Whs = R;

    const int b = blockIdx.x;
    const int q0 = blockIdx.y * 64;
    const int tid = threadIdx.x;
    const int tx = tid & 15, ty = tid >> 4;

    float t_acc[4][4];
#pragma unroll
    for (int i = 0; i < 4; ++i)
#pragma unroll
        for (int j = 0; j < 4; ++j) t_acc[i][j] = 0.f;

    for (int kc = 0; kc < 8; ++kc) {
        __syncthreads();
#pragma unroll
        for (int r = 0; r < 4; ++r) {
            int idx = tid + (r << 8);
            int q   = idx >> 4;
            int k0l = (idx & 15) << 2;
            float4 v = *reinterpret_cast<const float4*>(
                &attn[((size_t)b * SS + q0 + q) * SS + (kc << 6) + k0l]);
            AsT[(k0l + 0) * 68 + q] = v.x;
            AsT[(k0l + 1) * 68 + q] = v.y;
            AsT[(k0l + 2) * 68 + q] = v.z;
            AsT[(k0l + 3) * 68 + q] = v.w;
        }
#pragma unroll
        for (int r = 0; r < 4; ++r) {
            int idx = tid + (r << 8);
            int kk = idx >> 4;
            int d0 = (idx & 15) << 2;
            float4 v = *reinterpret_cast<const float4*>(
                &V[((size_t)b * SS + (kc << 6) + kk) * ADIM + d0]);
            *reinterpret_cast<float4*>(&Vs[kk * 68 + d0]) = v;
        }
        __syncthreads();
#pragma unroll 16
        for (int kk = 0; kk < 64; ++kk) {
            float4 a  = *reinterpret_cast<const float4*>(&AsT[kk * 68 + (ty << 2)]);
            float4 vv = *reinterpret_cast<const float4*>(&Vs[kk * 68 + (tx << 2)]);
            const float aa[4] = {a.x, a.y, a.z, a.w};
            const float va[4] = {vv.x, vv.y, vv.z, vv.w};
#pragma unroll
            for (int i = 0; i < 4; ++i)
#pragma unroll
                for (int j = 0; j < 4; ++j)
                    t_acc[i][j] += aa[i] * va[j];
        }
    }
    __syncthreads();
#pragma unroll
    for (int i = 0; i < 4; ++i)
#pragma unroll
        for (int j = 0; j < 4; ++j)
            UsT[(tx << 2) + j][(ty << 2) + i] = t_acc[i][j];

    float o_acc[4][16];
#pragma unroll
    for (int i = 0; i < 4; ++i)
#pragma unroll
        for (int t = 0; t < 16; ++t) o_acc[i][t] = 0.f;

    for (int dc = 0; dc < 2; ++dc) {
        __syncthreads();
#pragma unroll
        for (int r = 0; r < 8; ++r) {
            int idx = tid + (r << 8);
            int dl = idx >> 6;
            int n0 = (idx & 63) << 2;
            float4 w = *reinterpret_cast<const float4*>(
                &Wh[((size_t)((dc << 5) + dl)) * HIDD + n0]);
            *reinterpret_cast<float4*>(&Whs[dl * 260 + n0]) = w;
        }
        __syncthreads();
#pragma unroll 8
        for (int dl = 0; dl < 32; ++dl) {
            float4 u = *reinterpret_cast<const float4*>(&UsT[(dc << 5) + dl][ty << 2]);
            const float ua[4] = {u.x, u.y, u.z, u.w};
#pragma unroll
            for (int jj = 0; jj < 4; ++jj) {
                float4 w = *reinterpret_cast<const float4*>(&Whs[dl * 260 + (jj << 6) + (tx << 2)]);
                const float wa[4] = {w.x, w.y, w.z, w.w};
#pragma unroll
                for (int i = 0; i < 4; ++i) {
                    o_acc[i][(jj << 2) + 0] += ua[i] * wa[0];
                    o_acc[i][(jj << 2) + 1] += ua[i] * wa[1];
                    o_acc[i][(jj << 2) + 2] += ua[i] * wa[2];
                    o_acc[i][(jj << 2) + 3] += ua[i] * wa[3];
                }
            }
        }
    }

#pragma unroll
    for (int i = 0; i < 4; ++i) {
        const int q = q0 + (ty << 2) + i;
#pragma unroll
        for (int jj = 0; jj < 4; ++jj) {
            const int n = (jj << 6) + (tx << 2);
            float4 bv4 = *reinterpret_cast<const float4*>(&bh[n]);
            float4 o;
            o.x = o_acc[i][(jj << 2) + 0] + bv4.x;
            o.y = o_acc[i][(jj << 2) + 1] + bv4.y;
            o.z = o_acc[i][(jj << 2) + 2] + bv4.z;
            o.w = o_acc[i][(jj << 2) + 3] + bv4.w;
            *reinterpret_cast<float4*>(&out[((size_t)b * SS + q) * HIDD + n]) = o;
        }
    }
}

// ---------------------------------------------------------------------------
extern "C" void kernel_launch(void* const* d_in, const int* in_sizes, int n_in,
                              void* d_out, int out_size, void* d_ws, size_t ws_size,
                              hipStream_t stream)
{
    const float* query = (const float*)d_in[0];
    const float* key   = (const float*)d_in[1];
    const float* value = (const float*)d_in[2];
    const int*   mask  = (const int*)d_in[3];
    const float* Wq = (const float*)d_in[4];
    const float* bq = (const float*)d_in[5];
    const float* Wk = (const float*)d_in[6];
    const float* bk = (const float*)d_in[7];
    const float* Wv = (const float*)d_in[8];
    const float* bv = (const float*)d_in[9];
    const float* Wh = (const float*)d_in[10];
    const float* bh = (const float*)d_in[11];

    float* out  = (float*)d_out;                       // [B,S,HID]
    float* attn = out + (size_t)NB * SS * HIDD;        // [B,S,S]

    const size_t BS = (size_t)NB * SS;
    short* Qhi = (short*)d_ws;                         // frag-tiled [b][h][t16][ks2][64][8]
    short* Qlo = Qhi + BS * HIDD;
    short* Khi = Qlo + BS * HIDD;
    short* Klo = Khi + BS * HIDD;
    float* Vp  = (float*)(Klo + BS * HIDD);            // [BS, ADIM] fp32

    // WT lives at the head of the attn output region; qkv_gemm consumes it
    // before attn_probs_mfma overwrites that region. 576*256*2 shorts = 590KB.
    short* WT_hi = (short*)attn;
    short* WT_lo = WT_hi + NTOT * HIDD;

    prep_weights<<<dim3(NTOT), 256, 0, stream>>>(Wq, Wk, Wv, WT_hi, WT_lo);
    qkv_gemm<<<dim3(2304), 256, 0, stream>>>(query, key, value, WT_hi, WT_lo,
                                             bq, bk, bv, Qhi, Qlo, Khi, Klo, Vp);
    attn_probs_mfma<<<dim3(1024), 256, 0, stream>>>(Qhi, Qlo, Khi, Klo, mask, attn);
    attn_out_kernel<<<dim3(64, 8), 256, 0, stream>>>(attn, Vp, Wh, bh, out);
}

// Round 9
// 202.039 us; speedup vs baseline: 1.1021x; 1.1021x over previous
//
#include <hip/hip_runtime.h>

#define NB 64
#define SS 512
#define HIDD 256
#define NHEADS 4
#define ADIM 64
#define NTOT 576   // Wq(256) + Wk(256) + Wv(64) concatenated output cols

typedef __attribute__((ext_vector_type(8))) short short8v;
typedef __attribute__((ext_vector_type(4))) float f32x4;

#define MFMA16(A, B, C) __builtin_amdgcn_mfma_f32_16x16x32_bf16(A, B, C, 0, 0, 0)
#define AS1 __attribute__((address_space(1)))
#define AS3 __attribute__((address_space(3)))

// async 16B/lane global->LDS copy (dest = wave-uniform base + lane*16)
__device__ __forceinline__ void g2l16(void* lds, const void* g) {
    __builtin_amdgcn_global_load_lds((const AS1 unsigned*)g,
                                     (AS3 unsigned*)lds, 16, 0, 0);
}

// split fp32 x into bf16 hi + bf16 lo with x ~= hi + lo (error ~2^-17 rel)
__device__ __forceinline__ void bsplit(float x, short& hi, short& lo) {
    unsigned u = __float_as_uint(x);
    unsigned uh = (u + 0x8000u) & 0xFFFF0000u;
    hi = (short)(uh >> 16);
    float r = x - __uint_as_float(uh);
    lo = (short)((__float_as_uint(r) + 0x8000u) >> 16);
}

__device__ __forceinline__ void bsplit_v(float x, short8v& vh, short8v& vl, int i) {
    short h, l;
    bsplit(x, h, l);
    vh[i] = h;
    vl[i] = l;
}

// fragment-tiled Q/K address: [b][h][t16][ks2][lane][8], lane = rk + 16*lgk
__device__ __forceinline__ int frag_addr(int bb, int hh, int s, int d) {
    const int t16 = s >> 4, rk = s & 15;
    const int ks2 = d >> 5, lgk = (d >> 3) & 3, e8 = d & 7;
    return ((((bb * 4 + hh) * 32 + t16) * 2 + ks2) * 64 + rk + 16 * lgk) * 8 + e8;
}

// ---------------------------------------------------------------------------
// Pre-split + transpose weights: WT[n][k], n in [0,576): {Wq | Wk | Wv}
// ---------------------------------------------------------------------------
__global__ __launch_bounds__(256) void prep_weights(
    const float* __restrict__ Wq, const float* __restrict__ Wk,
    const float* __restrict__ Wv, short* __restrict__ WT_hi,
    short* __restrict__ WT_lo)
{
    const int idx = blockIdx.x * 256 + threadIdx.x;   // 576*256 elements
    const int n = idx >> 8, k = idx & 255;
    float v;
    if (n < 256)      v = Wq[k * 256 + n];
    else if (n < 512) v = Wk[k * 256 + (n - 256)];
    else              v = Wv[k * 64 + (n - 512)];
    short h, l;
    bsplit(v, h, l);
    WT_hi[idx] = h;
    WT_lo[idx] = l;
}

// ---------------------------------------------------------------------------
// Fused Q/K/V projection GEMM (MFMA split-bf16, 3-term), LDS-staged.
// BM=64: LDS 32KB -> 5 blocks/CU, VGPR ~56 -> deep cross-block overlap.
// grid (512, 9): nb 0-3 -> Q, 4-7 -> K, 8 -> V. Wave w owns 16 m-rows.
// ---------------------------------------------------------------------------
__global__ __launch_bounds__(256) void qkv_gemm(
    const float* __restrict__ query, const float* __restrict__ key,
    const float* __restrict__ value,
    const short* __restrict__ WT_hi, const short* __restrict__ WT_lo,
    const float* __restrict__ bq, const float* __restrict__ bk,
    const float* __restrict__ bv,
    short* __restrict__ Qhi, short* __restrict__ Qlo,
    short* __restrict__ Khi, short* __restrict__ Klo,
    float* __restrict__ V)
{
    __shared__ float Af[2][64 * 32];      // 8 KB per buffer
    __shared__ short Wh_s[2][64 * 32];    // 4 KB per buffer
    __shared__ short Wl_s[2][64 * 32];    // 4 KB per buffer

    const int bm = blockIdx.x * 64;
    const int nb = blockIdx.y;
    const int bn = nb * 64;
    const int tid = threadIdx.x;
    const int w = tid >> 6;
    const int l = tid & 63;
    const int l15 = l & 15, lg = l >> 4;
    const int wbase = tid & 192;          // w*64, wave-uniform

    const float* A = (nb < 4) ? query : (nb < 8) ? key : value;

    f32x4 acc[4];
#pragma unroll
    for (int j = 0; j < 4; ++j) acc[j] = (f32x4){0.f, 0.f, 0.f, 0.f};

    // ---- staging: A chunk [64][32] f32, WT chunk [64][32] hi+lo ----
    auto stage = [&](int buf, int kc) {
        const int k0 = kc * 32;
#pragma unroll
        for (int i = 0; i < 2; ++i) {
            const int g = i * 256 + tid;          // 16B-slot id, 0..511
            const int row = g >> 3;               // 0..63
            const int p = g & 7;                  // physical 16B slot in row
            const int sl = p ^ (row & 7);         // logical slot (source)
            g2l16(&Af[buf][(i * 256 + wbase) * 4],
                  A + (size_t)(bm + row) * HIDD + k0 + sl * 4);
        }
        {
            const int row = tid >> 2;             // 0..63
            const int p = tid & 3;
            const int sl = p ^ (row & 3);
            const size_t goff = (size_t)(bn + row) * HIDD + k0 + sl * 8;
            g2l16(&Wh_s[buf][wbase * 8], WT_hi + goff);
            g2l16(&Wl_s[buf][wbase * 8], WT_lo + goff);
        }
    };

    stage(0, 0);
    __syncthreads();   // compiler drains vmcnt(0) before s_barrier

    int cur = 0;
#pragma unroll
    for (int kc = 0; kc < 8; ++kc) {
        if (kc < 7) stage(cur ^ 1, kc + 1);   // prefetch overlaps compute

        // ---- A fragment from LDS (swizzled) + bsplit ----
        short8v ah, al;
        {
            const int rowA = w * 16 + l15;
            const int s0 = (lg * 2 + 0) ^ (rowA & 7);
            const int s1 = (lg * 2 + 1) ^ (rowA & 7);
            float4 a0 = *reinterpret_cast<const float4*>(&Af[cur][rowA * 32 + s0 * 4]);
            float4 a1 = *reinterpret_cast<const float4*>(&Af[cur][rowA * 32 + s1 * 4]);
            bsplit_v(a0.x, ah, al, 0);
            bsplit_v(a0.y, ah, al, 1);
            bsplit_v(a0.z, ah, al, 2);
            bsplit_v(a0.w, ah, al, 3);
            bsplit_v(a1.x, ah, al, 4);
            bsplit_v(a1.y, ah, al, 5);
            bsplit_v(a1.z, ah, al, 6);
            bsplit_v(a1.w, ah, al, 7);
        }

        // ---- WT fragments + MFMA (3-term split) ----
#pragma unroll
        for (int j = 0; j < 4; ++j) {
            const int rowB = j * 16 + l15;
            const int sl = lg ^ (rowB & 3);
            short8v bh = *reinterpret_cast<const short8v*>(&Wh_s[cur][rowB * 32 + sl * 8]);
            short8v bl = *reinterpret_cast<const short8v*>(&Wl_s[cur][rowB * 32 + sl * 8]);
            acc[j] = MFMA16(ah, bh, acc[j]);
            acc[j] = MFMA16(ah, bl, acc[j]);
            acc[j] = MFMA16(al, bh, acc[j]);
        }
        __syncthreads();   // waves done reading `cur`; prefetch landed
        cur ^= 1;
    }

    // ---- epilogue: bias + fragment-tiled split-store (Q/K) or fp32 (V) ----
    const float* biasp = (nb < 4) ? bq : (nb < 8) ? bk : bv;
    const int nloc_base = (nb < 4) ? bn : (nb < 8) ? bn - 256 : 0;
#pragma unroll
    for (int j = 0; j < 4; ++j) {
        const int ncol = nloc_base + j * 16 + l15;
        const float bias = biasp[ncol];
        if (nb < 8) {
            short* Dhi = (nb < 4) ? Qhi : Khi;
            short* Dlo = (nb < 4) ? Qlo : Klo;
#pragma unroll
            for (int r = 0; r < 4; ++r) {
                const int m = bm + w * 16 + lg * 4 + r;
                const int bb = m >> 9, s = m & 511;
                const int hh = ncol >> 6, dd = ncol & 63;
                const int fa = frag_addr(bb, hh, s, dd);
                short h, lo_;
                bsplit(acc[j][r] + bias, h, lo_);
                Dhi[fa] = h;
                Dlo[fa] = lo_;
            }
        } else {
#pragma unroll
            for (int r = 0; r < 4; ++r) {
                const int m = bm + w * 16 + lg * 4 + r;
                V[(size_t)m * ADIM + ncol] = acc[j][r] + bias;
            }
        }
    }
}

// ---------------------------------------------------------------------------
// attn[b,q,k] = mean_h softmax_k( mask ? (Q_h . K_h)/8 : -inf )
// MFMA split-bf16; Q/K in fragment-tiled layout -> every fragment load is
// one coalesced 1KB wave read (base + lane*16B). Direct global (r7 structure;
// LDS staging measured slower). No row-max (shift-invariant, |e*c| bounded).
// ---------------------------------------------------------------------------
__global__ __launch_bounds__(256) void attn_probs_mfma(
    const short* __restrict__ Qhi_g, const short* __restrict__ Qlo_g,
    const short* __restrict__ Khi_g, const short* __restrict__ Klo_g,
    const int* __restrict__ mask, float* __restrict__ attn)
{
    __shared__ float red[2][4][2][16];

    // bijective XCD swizzle: 1024 blocks = 8 xcds x 128
    const int wg = blockIdx.x;
    const int swz = (wg & 7) * 128 + (wg >> 3);
    const int b = swz >> 4;
    const int q0 = (swz & 15) * 32;

    const int tid = threadIdx.x;
    const int w = tid >> 6;          // wave 0..3 -> k-subtiles {2w, 2w+1} per 128-tile
    const int l = tid & 63;
    const int l15 = l & 15;
    const int lg = l >> 4;

    // ---- pack mask bits: per lane, per qs: 8 frags x 4 k-bits ----
    unsigned mbits[2];
#pragma unroll
    for (int qs = 0; qs < 2; ++qs) {
        unsigned bits = 0;
        const int q = q0 + qs * 16 + l15;
        const int* mrow = mask + ((size_t)b * SS + q) * SS;
#pragma unroll
        for (int f = 0; f < 8; ++f) {
            const int kt = f >> 1, ms = f & 1;
            const int k = kt * 128 + (2 * w + ms) * 16 + lg * 4;
            int4 mv = *reinterpret_cast<const int4*>(&mrow[k]);
            bits |= (mv.x != 0 ? 1u : 0u) << (f * 4 + 0);
            bits |= (mv.y != 0 ? 1u : 0u) << (f * 4 + 1);
            bits |= (mv.z != 0 ? 1u : 0u) << (f * 4 + 2);
            bits |= (mv.w != 0 ? 1u : 0u) << (f * 4 + 3);
        }
        mbits[qs] = bits;
    }

    f32x4 acc[4][2][2];
#pragma unroll
    for (int kt = 0; kt < 4; ++kt)
#pragma unroll
        for (int ms = 0; ms < 2; ++ms)
#pragma unroll
            for (int qs = 0; qs < 2; ++qs)
                acc[kt][ms][qs] = (f32x4){0.f, 0.f, 0.f, 0.f};

    const int qt_base = (swz & 15) * 2;   // q-tile16 index base

    for (int h = 0; h < NHEADS; ++h) {
        const int bh32 = (b * 4 + h) * 32;

        // ---- Q fragments: coalesced frag-tile loads, reused across k ----
        short8v qh[2][2], ql[2][2];
#pragma unroll
        for (int ks2 = 0; ks2 < 2; ++ks2)
#pragma unroll
            for (int qs = 0; qs < 2; ++qs) {
                const int off = (((bh32 + qt_base + qs) * 2 + ks2) * 64 + l) * 8;
                qh[ks2][qs] = *reinterpret_cast<const short8v*>(Qhi_g + off);
                ql[ks2][qs] = *reinterpret_cast<const short8v*>(Qlo_g + off);
            }

        f32x4 e[4][2][2];
#pragma unroll
        for (int kt = 0; kt < 4; ++kt)
#pragma unroll
            for (int ms = 0; ms < 2; ++ms)
#pragma unroll
                for (int qs = 0; qs < 2; ++qs)
                    e[kt][ms][qs] = (f32x4){0.f, 0.f, 0.f, 0.f};

#pragma unroll
        for (int kt = 0; kt < 4; ++kt) {
#pragma unroll
            for (int ks2 = 0; ks2 < 2; ++ks2) {
                const int t0 = kt * 8 + 2 * w;
                const int base0 = (((bh32 + t0) * 2 + ks2) * 64 + l) * 8;
                const int base1 = base0 + 1024;   // t16 + 1
                short8v ah0 = *reinterpret_cast<const short8v*>(Khi_g + base0);
                short8v ah1 = *reinterpret_cast<const short8v*>(Khi_g + base1);
                short8v al0 = *reinterpret_cast<const short8v*>(Klo_g + base0);
                short8v al1 = *reinterpret_cast<const short8v*>(Klo_g + base1);

                e[kt][0][0] = MFMA16(ah0, qh[ks2][0], e[kt][0][0]);
                e[kt][0][0] = MFMA16(ah0, ql[ks2][0], e[kt][0][0]);
                e[kt][0][0] = MFMA16(al0, qh[ks2][0], e[kt][0][0]);

                e[kt][0][1] = MFMA16(ah0, qh[ks2][1], e[kt][0][1]);
                e[kt][0][1] = MFMA16(ah0, ql[ks2][1], e[kt][0][1]);
                e[kt][0][1] = MFMA16(al0, qh[ks2][1], e[kt][0][1]);

                e[kt][1][0] = MFMA16(ah1, qh[ks2][0], e[kt][1][0]);
                e[kt][1][0] = MFMA16(ah1, ql[ks2][0], e[kt][1][0]);
                e[kt][1][0] = MFMA16(al1, qh[ks2][0], e[kt][1][0]);

                e[kt][1][1] = MFMA16(ah1, qh[ks2][1], e[kt][1][1]);
                e[kt][1][1] = MFMA16(ah1, ql[ks2][1], e[kt][1][1]);
                e[kt][1][1] = MFMA16(al1, qh[ks2][1], e[kt][1][1]);
            }
        }

        // ---- masked exp (no max shift) + sum + head-mean accumulate ----
        float sm[2] = {0.f, 0.f};
        const float c2 = 0.18033688011112042f;   // 0.125 * log2(e)
#pragma unroll
        for (int kt = 0; kt < 4; ++kt)
#pragma unroll
            for (int ms = 0; ms < 2; ++ms)
#pragma unroll
                for (int qs = 0; qs < 2; ++qs)
#pragma unroll
                    for (int r = 0; r < 4; ++r) {
                        float p = exp2f(e[kt][ms][qs][r] * c2);
                        const unsigned bit = (mbits[qs] >> ((kt * 2 + ms) * 4 + r)) & 1u;
                        p = bit ? p : 0.f;
                        e[kt][ms][qs][r] = p;
                        sm[qs] += p;
                    }
#pragma unroll
        for (int qs = 0; qs < 2; ++qs) {
            sm[qs] += __shfl_xor(sm[qs], 16);
            sm[qs] += __shfl_xor(sm[qs], 32);
        }
        if (l < 16) { red[h & 1][w][0][l] = sm[0]; red[h & 1][w][1][l] = sm[1]; }
        __syncthreads();
#pragma unroll
        for (int qs = 0; qs < 2; ++qs) {
            const float Z = (red[h & 1][0][qs][l15] + red[h & 1][1][qs][l15]) +
                            (red[h & 1][2][qs][l15] + red[h & 1][3][qs][l15]);
            const float inv = 0.25f / fmaxf(Z, 1e-30f);
#pragma unroll
            for (int kt = 0; kt < 4; ++kt)
#pragma unroll
                for (int ms = 0; ms < 2; ++ms)
#pragma unroll
                    for (int r = 0; r < 4; ++r)
                        acc[kt][ms][qs][r] += e[kt][ms][qs][r] * inv;
        }
    }

    // ---- write attention tile ----
#pragma unroll
    for (int kt = 0; kt < 4; ++kt)
#pragma unroll
        for (int ms = 0; ms < 2; ++ms)
#pragma unroll
            for (int qs = 0; qs < 2; ++qs) {
                const int q = q0 + qs * 16 + l15;
                const int k = kt * 128 + (2 * w + ms) * 16 + lg * 4;
                float4 o;
                o.x = acc[kt][ms][qs][0];
                o.y = acc[kt][ms][qs][1];
                o.z = acc[kt][ms][qs][2];
                o.w = acc[kt][ms][qs][3];
                *reinterpret_cast<float4*>(&attn[((size_t)b * SS + q) * SS + k]) = o;
            }
}

// ---------------------------------------------------------------------------
// B2: out[b,q,:] = (attention[b,q,:] @ V[b]) @ Wh + bh
// ---------------------------------------------------------------------------
__global__ __launch_bounds__(256) void attn_out_kernel(
    const float* __restrict__ attn, const float* __restrict__ V,
    const float* __restrict__ Wh, const float* __restrict__ bh,
    float* __restrict__ out)
{
    __shared__ float UsT[64][68];
    __shared__ float R[64 * 68 * 2];
    float* AsT = R;
    float* Vs  = R + 64 * 68;
    float* Whs = R;

    const int b = blockIdx.x;
    const int q0 = blockIdx.y * 64;
    const int tid = threadIdx.x;
    const int tx = tid & 15, ty = tid >> 4;

    float t_acc[4][4];
#pragma unroll
    for (int i = 0; i < 4; ++i)
#pragma unroll
        for (int j = 0; j < 4; ++j) t_acc[i][j] = 0.f;

    for (int kc = 0; kc < 8; ++kc) {
        __syncthreads();
#pragma unroll
        for (int r = 0; r < 4; ++r) {
            int idx = tid + (r << 8);
            int q   = idx >> 4;
            int k0l = (idx & 15) << 2;
            float4 v = *reinterpret_cast<const float4*>(
                &attn[((size_t)b * SS + q0 + q) * SS + (kc << 6) + k0l]);
            AsT[(k0l + 0) * 68 + q] = v.x;
            AsT[(k0l + 1) * 68 + q] = v.y;
            AsT[(k0l + 2) * 68 + q] = v.z;
            AsT[(k0l + 3) * 68 + q] = v.w;
        }
#pragma unroll
        for (int r = 0; r < 4; ++r) {
            int idx = tid + (r << 8);
            int kk = idx >> 4;
            int d0 = (idx & 15) << 2;
            float4 v = *reinterpret_cast<const float4*>(
                &V[((size_t)b * SS + (kc << 6) + kk) * ADIM + d0]);
            *reinterpret_cast<float4*>(&Vs[kk * 68 + d0]) = v;
        }
        __syncthreads();
#pragma unroll 16
        for (int kk = 0; kk < 64; ++kk) {
            float4 a  = *reinterpret_cast<const float4*>(&AsT[kk * 68 + (ty << 2)]);
            float4 vv = *reinterpret_cast<const float4*>(&Vs[kk * 68 + (tx << 2)]);
            const float aa[4] = {a.x, a.y, a.z, a.w};
            const float va[4] = {vv.x, vv.y, vv.z, vv.w};
#pragma unroll
            for (int i = 0; i < 4; ++i)
#pragma unroll
                for (int j = 0; j < 4; ++j)
                    t_acc[i][j] += aa[i] * va[j];
        }
    }
    __syncthreads();
#pragma unroll
    for (int i = 0; i < 4; ++i)
#pragma unroll
        for (int j = 0; j < 4; ++j)
            UsT[(tx << 2) + j][(ty << 2) + i] = t_acc[i][j];

    float o_acc[4][16];
#pragma unroll
    for (int i = 0; i < 4; ++i)
#pragma unroll
        for (int t = 0; t < 16; ++t) o_acc[i][t] = 0.f;

    for (int dc = 0; dc < 2; ++dc) {
        __syncthreads();
#pragma unroll
        for (int r = 0; r < 8; ++r) {
            int idx = tid + (r << 8);
            int dl = idx >> 6;
            int n0 = (idx & 63) << 2;
            float4 w = *reinterpret_cast<const float4*>(
                &Wh[((size_t)((dc << 5) + dl)) * HIDD + n0]);
            *reinterpret_cast<float4*>(&Whs[dl * 260 + n0]) = w;
        }
        __syncthreads();
#pragma unroll 8
        for (int dl = 0; dl < 32; ++dl) {
            float4 u = *reinterpret_cast<const float4*>(&UsT[(dc << 5) + dl][ty << 2]);
            const float ua[4] = {u.x, u.y, u.z, u.w};
#pragma unroll
            for (int jj = 0; jj < 4; ++jj) {
                float4 w = *reinterpret_cast<const float4*>(&Whs[dl * 260 + (jj << 6) + (tx << 2)]);
                const float wa[4] = {w.x, w.y, w.z, w.w};
#pragma unroll
                for (int i = 0; i < 4; ++i) {
                    o_acc[i][(jj << 2) + 0] += ua[i] * wa[0];
                    o_acc[i][(jj << 2) + 1] += ua[i] * wa[1];
                    o_acc[i][(jj << 2) + 2] += ua[i] * wa[2];
                    o_acc[i][(jj << 2) + 3] += ua[i] * wa[3];
                }
            }
        }
    }

#pragma unroll
    for (int i = 0; i < 4; ++i) {
        const int q = q0 + (ty << 2) + i;
#pragma unroll
        for (int jj = 0; jj < 4; ++jj) {
            const int n = (jj << 6) + (tx << 2);
            float4 bv4 = *reinterpret_cast<const float4*>(&bh[n]);
            float4 o;
            o.x = o_acc[i][(jj << 2) + 0] + bv4.x;
            o.y = o_acc[i][(jj << 2) + 1] + bv4.y;
            o.z = o_acc[i][(jj << 2) + 2] + bv4.z;
            o.w = o_acc[i][(jj << 2) + 3] + bv4.w;
            *reinterpret_cast<float4*>(&out[((size_t)b * SS + q) * HIDD + n]) = o;
        }
    }
}

// ---------------------------------------------------------------------------
extern "C" void kernel_launch(void* const* d_in, const int* in_sizes, int n_in,
                              void* d_out, int out_size, void* d_ws, size_t ws_size,
                              hipStream_t stream)
{
    const float* query = (const float*)d_in[0];
    const float* key   = (const float*)d_in[1];
    const float* value = (const float*)d_in[2];
    const int*   mask  = (const int*)d_in[3];
    const float* Wq = (const float*)d_in[4];
    const float* bq = (const float*)d_in[5];
    const float* Wk = (const float*)d_in[6];
    const float* bk = (const float*)d_in[7];
    const float* Wv = (const float*)d_in[8];
    const float* bv = (const float*)d_in[9];
    const float* Wh = (const float*)d_in[10];
    const float* bh = (const float*)d_in[11];

    float* out  = (float*)d_out;                       // [B,S,HID]
    float* attn = out + (size_t)NB * SS * HIDD;        // [B,S,S]

    const size_t BS = (size_t)NB * SS;
    short* Qhi = (short*)d_ws;                         // frag-tiled [b][h][t16][ks2][64][8]
    short* Qlo = Qhi + BS * HIDD;
    short* Khi = Qlo + BS * HIDD;
    short* Klo = Khi + BS * HIDD;
    float* Vp  = (float*)(Klo + BS * HIDD);            // [BS, ADIM] fp32

    // WT lives at the head of the attn output region; qkv_gemm consumes it
    // before attn_probs_mfma overwrites that region. 576*256*2 shorts = 590KB.
    short* WT_hi = (short*)attn;
    short* WT_lo = WT_hi + NTOT * HIDD;

    prep_weights<<<dim3(NTOT), 256, 0, stream>>>(Wq, Wk, Wv, WT_hi, WT_lo);
    qkv_gemm<<<dim3(512, 9), 256, 0, stream>>>(query, key, value, WT_hi, WT_lo,
                                               bq, bk, bv, Qhi, Qlo, Khi, Klo, Vp);
    attn_probs_mfma<<<dim3(1024), 256, 0, stream>>>(Qhi, Qlo, Khi, Klo, mask, attn);
    attn_out_kernel<<<dim3(64, 8), 256, 0, stream>>>(attn, Vp, Wh, bh, out);
}

// Round 10
// 186.206 us; speedup vs baseline: 1.1959x; 1.0850x over previous
//
#include <hip/hip_runtime.h>

#define NB 64
#define SS 512
#define HIDD 256
#define NHEADS 4
#define ADIM 64
#define NTOT 576   // Wq(256) + Wk(256) + Wv(64) concatenated output cols

typedef __attribute__((ext_vector_type(8))) short short8v;
typedef __attribute__((ext_vector_type(4))) float f32x4;

#define MFMA16(A, B, C) __builtin_amdgcn_mfma_f32_16x16x32_bf16(A, B, C, 0, 0, 0)
#define AS1 __attribute__((address_space(1)))
#define AS3 __attribute__((address_space(3)))

// async 16B/lane global->LDS copy (dest = wave-uniform base + lane*16)
__device__ __forceinline__ void g2l16(void* lds, const void* g) {
    __builtin_amdgcn_global_load_lds((const AS1 unsigned*)g,
                                     (AS3 unsigned*)lds, 16, 0, 0);
}

// split fp32 x into bf16 hi + bf16 lo with x ~= hi + lo (error ~2^-17 rel)
__device__ __forceinline__ void bsplit(float x, short& hi, short& lo) {
    unsigned u = __float_as_uint(x);
    unsigned uh = (u + 0x8000u) & 0xFFFF0000u;
    hi = (short)(uh >> 16);
    float r = x - __uint_as_float(uh);
    lo = (short)((__float_as_uint(r) + 0x8000u) >> 16);
}

__device__ __forceinline__ void bsplit_v(float x, short8v& vh, short8v& vl, int i) {
    short h, l;
    bsplit(x, h, l);
    vh[i] = h;
    vl[i] = l;
}

// ---------------------------------------------------------------------------
// Pre-split + transpose weights: WT[n][k], n in [0,576): {Wq | Wk | Wv}
// ---------------------------------------------------------------------------
__global__ __launch_bounds__(256) void prep_weights(
    const float* __restrict__ Wq, const float* __restrict__ Wk,
    const float* __restrict__ Wv, short* __restrict__ WT_hi,
    short* __restrict__ WT_lo)
{
    const int idx = blockIdx.x * 256 + threadIdx.x;   // 576*256 elements
    const int n = idx >> 8, k = idx & 255;
    float v;
    if (n < 256)      v = Wq[k * 256 + n];
    else if (n < 512) v = Wk[k * 256 + (n - 256)];
    else              v = Wv[k * 64 + (n - 512)];
    short h, l;
    bsplit(v, h, l);
    WT_hi[idx] = h;
    WT_lo[idx] = l;
}

// ---------------------------------------------------------------------------
// Fused Q/K/V projection GEMM (MFMA split-bf16, 3-term), LDS-staged.
// BM=64, grid (512, 9): nb 0-3 -> Q, 4-7 -> K, 8 -> V.
// Q/K epilogue: acc -> LDS (frag order) -> contiguous 16KB coalesced stores.
// ---------------------------------------------------------------------------
__global__ __launch_bounds__(256) void qkv_gemm(
    const float* __restrict__ query, const float* __restrict__ key,
    const float* __restrict__ value,
    const short* __restrict__ WT_hi, const short* __restrict__ WT_lo,
    const float* __restrict__ bq, const float* __restrict__ bk,
    const float* __restrict__ bv,
    short* __restrict__ Qhi, short* __restrict__ Qlo,
    short* __restrict__ Khi, short* __restrict__ Klo,
    float* __restrict__ V)
{
    __shared__ float Af[2][64 * 32];      // 8 KB per buffer; reused by epilogue
    __shared__ short Wh_s[2][64 * 32];    // 4 KB per buffer
    __shared__ short Wl_s[2][64 * 32];    // 4 KB per buffer

    const int bm = blockIdx.x * 64;
    const int nb = blockIdx.y;
    const int bn = nb * 64;
    const int tid = threadIdx.x;
    const int w = tid >> 6;
    const int l = tid & 63;
    const int l15 = l & 15, lg = l >> 4;
    const int wbase = tid & 192;          // w*64, wave-uniform

    const float* A = (nb < 4) ? query : (nb < 8) ? key : value;

    f32x4 acc[4];
#pragma unroll
    for (int j = 0; j < 4; ++j) acc[j] = (f32x4){0.f, 0.f, 0.f, 0.f};

    // ---- staging: A chunk [64][32] f32, WT chunk [64][32] hi+lo ----
    auto stage = [&](int buf, int kc) {
        const int k0 = kc * 32;
#pragma unroll
        for (int i = 0; i < 2; ++i) {
            const int g = i * 256 + tid;          // 16B-slot id, 0..511
            const int row = g >> 3;               // 0..63
            const int p = g & 7;                  // physical 16B slot in row
            const int sl = p ^ (row & 7);         // logical slot (source)
            g2l16(&Af[buf][(i * 256 + wbase) * 4],
                  A + (size_t)(bm + row) * HIDD + k0 + sl * 4);
        }
        {
            const int row = tid >> 2;             // 0..63
            const int p = tid & 3;
            const int sl = p ^ (row & 3);
            const size_t goff = (size_t)(bn + row) * HIDD + k0 + sl * 8;
            g2l16(&Wh_s[buf][wbase * 8], WT_hi + goff);
            g2l16(&Wl_s[buf][wbase * 8], WT_lo + goff);
        }
    };

    stage(0, 0);
    __syncthreads();   // compiler drains vmcnt(0) before s_barrier

    int cur = 0;
#pragma unroll
    for (int kc = 0; kc < 8; ++kc) {
        if (kc < 7) stage(cur ^ 1, kc + 1);   // prefetch overlaps compute

        // ---- A fragment from LDS (swizzled) + bsplit ----
        short8v ah, al;
        {
            const int rowA = w * 16 + l15;
            const int s0 = (lg * 2 + 0) ^ (rowA & 7);
            const int s1 = (lg * 2 + 1) ^ (rowA & 7);
            float4 a0 = *reinterpret_cast<const float4*>(&Af[cur][rowA * 32 + s0 * 4]);
            float4 a1 = *reinterpret_cast<const float4*>(&Af[cur][rowA * 32 + s1 * 4]);
            bsplit_v(a0.x, ah, al, 0);
            bsplit_v(a0.y, ah, al, 1);
            bsplit_v(a0.z, ah, al, 2);
            bsplit_v(a0.w, ah, al, 3);
            bsplit_v(a1.x, ah, al, 4);
            bsplit_v(a1.y, ah, al, 5);
            bsplit_v(a1.z, ah, al, 6);
            bsplit_v(a1.w, ah, al, 7);
        }

        // ---- WT fragments + MFMA (3-term split) ----
#pragma unroll
        for (int j = 0; j < 4; ++j) {
            const int rowB = j * 16 + l15;
            const int sl = lg ^ (rowB & 3);
            short8v bh = *reinterpret_cast<const short8v*>(&Wh_s[cur][rowB * 32 + sl * 8]);
            short8v bl = *reinterpret_cast<const short8v*>(&Wl_s[cur][rowB * 32 + sl * 8]);
            acc[j] = MFMA16(ah, bh, acc[j]);
            acc[j] = MFMA16(ah, bl, acc[j]);
            acc[j] = MFMA16(al, bh, acc[j]);
        }
        __syncthreads();   // waves done reading `cur`; prefetch landed
        cur ^= 1;
    }

    // ---- epilogue ----
    if (nb < 8) {
        // Q/K: acc -> LDS in frag order -> contiguous coalesced stores.
        // Block output = one (b, head): 4 t16-slabs, 16KB total (hi) + 16KB (lo)
        // frag local idx: ((w*2 + ks2)*64 + rk + 16*lgk)*8 + e8, rk = lg*4+r
        short* Lhi = reinterpret_cast<short*>(&Af[0][0]);   // 4096 shorts = 8KB
        short* Llo = Lhi + 4096;                            // 8KB
        const float* biasp = (nb < 4) ? bq : bk;
        const int nloc_base = (nb < 4) ? bn : bn - 256;
#pragma unroll
        for (int j = 0; j < 4; ++j) {
            const int dd = (nloc_base + j * 16 + l15) & 63;
            const float bias = biasp[nloc_base + j * 16 + l15];
            const int ks2 = dd >> 5, lgk = (dd >> 3) & 3, e8 = dd & 7;
#pragma unroll
            for (int r = 0; r < 4; ++r) {
                const int li = ((w * 2 + ks2) * 64 + lg * 4 + r + 16 * lgk) * 8 + e8;
                short h, lo_;
                bsplit(acc[j][r] + bias, h, lo_);
                Lhi[li] = h;
                Llo[li] = lo_;
            }
        }
        __syncthreads();
        short* Dhi = (nb < 4) ? Qhi : Khi;
        short* Dlo = (nb < 4) ? Qlo : Klo;
        const int bb = bm >> 9;
        const int hh = nloc_base >> 6;
        const int t16_0 = (bm & 511) >> 4;
        const size_t gbase = ((size_t)(bb * 4 + hh) * 32 + t16_0) * 1024;  // shorts
#pragma unroll
        for (int i = 0; i < 2; ++i) {
            const int c8 = i * 256 + tid;   // 16B chunk id, 0..511
            *reinterpret_cast<int4*>(Dhi + gbase + c8 * 8) =
                *reinterpret_cast<const int4*>(Lhi + c8 * 8);
            *reinterpret_cast<int4*>(Dlo + gbase + c8 * 8) =
                *reinterpret_cast<const int4*>(Llo + c8 * 8);
        }
    } else {
        // V: fp32 row-major stores (64B-contiguous per quarter-wave)
#pragma unroll
        for (int j = 0; j < 4; ++j) {
            const int ncol = j * 16 + l15;
            const float bias = bv[ncol];
#pragma unroll
            for (int r = 0; r < 4; ++r) {
                const int m = bm + w * 16 + lg * 4 + r;
                V[(size_t)m * ADIM + ncol] = acc[j][r] + bias;
            }
        }
    }
}

// ---------------------------------------------------------------------------
// attn[b,q,k] = mean_h softmax_k( mask ? (Q_h . K_h)/8 : -inf )
// MFMA split-bf16; Q/K in fragment-tiled layout -> every fragment load is
// one coalesced 1KB wave read (base + lane*16B). Direct global (r7 structure;
// LDS staging measured slower). No row-max (shift-invariant, |e*c| bounded).
// ---------------------------------------------------------------------------
__global__ __launch_bounds__(256) void attn_probs_mfma(
    const short* __restrict__ Qhi_g, const short* __restrict__ Qlo_g,
    const short* __restrict__ Khi_g, const short* __restrict__ Klo_g,
    const int* __restrict__ mask, float* __restrict__ attn)
{
    __shared__ float red[2][4][2][16];

    // bijective XCD swizzle: 1024 blocks = 8 xcds x 128
    const int wg = blockIdx.x;
    const int swz = (wg & 7) * 128 + (wg >> 3);
    const int b = swz >> 4;
    const int q0 = (swz & 15) * 32;

    const int tid = threadIdx.x;
    const int w = tid >> 6;          // wave 0..3 -> k-subtiles {2w, 2w+1} per 128-tile
    const int l = tid & 63;
    const int l15 = l & 15;
    const int lg = l >> 4;

    // ---- pack mask bits: per lane, per qs: 8 frags x 4 k-bits ----
    unsigned mbits[2];
#pragma unroll
    for (int qs = 0; qs < 2; ++qs) {
        unsigned bits = 0;
        const int q = q0 + qs * 16 + l15;
        const int* mrow = mask + ((size_t)b * SS + q) * SS;
#pragma unroll
        for (int f = 0; f < 8; ++f) {
            const int kt = f >> 1, ms = f & 1;
            const int k = kt * 128 + (2 * w + ms) * 16 + lg * 4;
            int4 mv = *reinterpret_cast<const int4*>(&mrow[k]);
            bits |= (mv.x != 0 ? 1u : 0u) << (f * 4 + 0);
            bits |= (mv.y != 0 ? 1u : 0u) << (f * 4 + 1);
            bits |= (mv.z != 0 ? 1u : 0u) << (f * 4 + 2);
            bits |= (mv.w != 0 ? 1u : 0u) << (f * 4 + 3);
        }
        mbits[qs] = bits;
    }

    f32x4 acc[4][2][2];
#pragma unroll
    for (int kt = 0; kt < 4; ++kt)
#pragma unroll
        for (int ms = 0; ms < 2; ++ms)
#pragma unroll
            for (int qs = 0; qs < 2; ++qs)
                acc[kt][ms][qs] = (f32x4){0.f, 0.f, 0.f, 0.f};

    const int qt_base = (swz & 15) * 2;   // q-tile16 index base

    for (int h = 0; h < NHEADS; ++h) {
        const int bh32 = (b * 4 + h) * 32;

        // ---- Q fragments: coalesced frag-tile loads, reused across k ----
        short8v qh[2][2], ql[2][2];
#pragma unroll
        for (int ks2 = 0; ks2 < 2; ++ks2)
#pragma unroll
            for (int qs = 0; qs < 2; ++qs) {
                const int off = (((bh32 + qt_base + qs) * 2 + ks2) * 64 + l) * 8;
                qh[ks2][qs] = *reinterpret_cast<const short8v*>(Qhi_g + off);
                ql[ks2][qs] = *reinterpret_cast<const short8v*>(Qlo_g + off);
            }

        f32x4 e[4][2][2];
#pragma unroll
        for (int kt = 0; kt < 4; ++kt)
#pragma unroll
            for (int ms = 0; ms < 2; ++ms)
#pragma unroll
                for (int qs = 0; qs < 2; ++qs)
                    e[kt][ms][qs] = (f32x4){0.f, 0.f, 0.f, 0.f};

#pragma unroll
        for (int kt = 0; kt < 4; ++kt) {
#pragma unroll
            for (int ks2 = 0; ks2 < 2; ++ks2) {
                const int t0 = kt * 8 + 2 * w;
                const int base0 = (((bh32 + t0) * 2 + ks2) * 64 + l) * 8;
                const int base1 = base0 + 1024;   // t16 + 1
                short8v ah0 = *reinterpret_cast<const short8v*>(Khi_g + base0);
                short8v ah1 = *reinterpret_cast<const short8v*>(Khi_g + base1);
                short8v al0 = *reinterpret_cast<const short8v*>(Klo_g + base0);
                short8v al1 = *reinterpret_cast<const short8v*>(Klo_g + base1);

                e[kt][0][0] = MFMA16(ah0, qh[ks2][0], e[kt][0][0]);
                e[kt][0][0] = MFMA16(ah0, ql[ks2][0], e[kt][0][0]);
                e[kt][0][0] = MFMA16(al0, qh[ks2][0], e[kt][0][0]);

                e[kt][0][1] = MFMA16(ah0, qh[ks2][1], e[kt][0][1]);
                e[kt][0][1] = MFMA16(ah0, ql[ks2][1], e[kt][0][1]);
                e[kt][0][1] = MFMA16(al0, qh[ks2][1], e[kt][0][1]);

                e[kt][1][0] = MFMA16(ah1, qh[ks2][0], e[kt][1][0]);
                e[kt][1][0] = MFMA16(ah1, ql[ks2][0], e[kt][1][0]);
                e[kt][1][0] = MFMA16(al1, qh[ks2][0], e[kt][1][0]);

                e[kt][1][1] = MFMA16(ah1, qh[ks2][1], e[kt][1][1]);
                e[kt][1][1] = MFMA16(ah1, ql[ks2][1], e[kt][1][1]);
                e[kt][1][1] = MFMA16(al1, qh[ks2][1], e[kt][1][1]);
            }
        }

        // ---- masked exp (no max shift) + sum + head-mean accumulate ----
        float sm[2] = {0.f, 0.f};
        const float c = 0.125f;
#pragma unroll
        for (int kt = 0; kt < 4; ++kt)
#pragma unroll
            for (int ms = 0; ms < 2; ++ms)
#pragma unroll
                for (int qs = 0; qs < 2; ++qs)
#pragma unroll
                    for (int r = 0; r < 4; ++r) {
                        float p = __expf(e[kt][ms][qs][r] * c);
                        const unsigned bit = (mbits[qs] >> ((kt * 2 + ms) * 4 + r)) & 1u;
                        p = bit ? p : 0.f;
                        e[kt][ms][qs][r] = p;
                        sm[qs] += p;
                    }
#pragma unroll
        for (int qs = 0; qs < 2; ++qs) {
            sm[qs] += __shfl_xor(sm[qs], 16);
            sm[qs] += __shfl_xor(sm[qs], 32);
        }
        if (l < 16) { red[h & 1][w][0][l] = sm[0]; red[h & 1][w][1][l] = sm[1]; }
        __syncthreads();
#pragma unroll
        for (int qs = 0; qs < 2; ++qs) {
            const float Z = (red[h & 1][0][qs][l15] + red[h & 1][1][qs][l15]) +
                            (red[h & 1][2][qs][l15] + red[h & 1][3][qs][l15]);
            const float inv = 0.25f / fmaxf(Z, 1e-30f);
#pragma unroll
            for (int kt = 0; kt < 4; ++kt)
#pragma unroll
                for (int ms = 0; ms < 2; ++ms)
#pragma unroll
                    for (int r = 0; r < 4; ++r)
                        acc[kt][ms][qs][r] += e[kt][ms][qs][r] * inv;
        }
    }

    // ---- write attention tile ----
#pragma unroll
    for (int kt = 0; kt < 4; ++kt)
#pragma unroll
        for (int ms = 0; ms < 2; ++ms)
#pragma unroll
            for (int qs = 0; qs < 2; ++qs) {
                const int q = q0 + qs * 16 + l15;
                const int k = kt * 128 + (2 * w + ms) * 16 + lg * 4;
                float4 o;
                o.x = acc[kt][ms][qs][0];
                o.y = acc[kt][ms][qs][1];
                o.z = acc[kt][ms][qs][2];
                o.w = acc[kt][ms][qs][3];
                *reinterpret_cast<float4*>(&attn[((size_t)b * SS + q) * SS + k]) = o;
            }
}

// ---------------------------------------------------------------------------
// B2: out[b,q,:] = (attention[b,q,:] @ V[b]) @ Wh + bh
// ---------------------------------------------------------------------------
__global__ __launch_bounds__(256) void attn_out_kernel(
    const float* __restrict__ attn, const float* __restrict__ V,
    const float* __restrict__ Wh, const float* __restrict__ bh,
    float* __restrict__ out)
{
    __shared__ float UsT[64][68];
    __shared__ float R[64 * 68 * 2];
    float* AsT = R;
    float* Vs  = R + 64 * 68;
    float* Whs = R;

    const int b = blockIdx.x;
    const int q0 = blockIdx.y * 64;
    const int tid = threadIdx.x;
    const int tx = tid & 15, ty = tid >> 4;

    float t_acc[4][4];
#pragma unroll
    for (int i = 0; i < 4; ++i)
#pragma unroll
        for (int j = 0; j < 4; ++j) t_acc[i][j] = 0.f;

    for (int kc = 0; kc < 8; ++kc) {
        __syncthreads();
#pragma unroll
        for (int r = 0; r < 4; ++r) {
            int idx = tid + (r << 8);
            int q   = idx >> 4;
            int k0l = (idx & 15) << 2;
            float4 v = *reinterpret_cast<const float4*>(
                &attn[((size_t)b * SS + q0 + q) * SS + (kc << 6) + k0l]);
            AsT[(k0l + 0) * 68 + q] = v.x;
            AsT[(k0l + 1) * 68 + q] = v.y;
            AsT[(k0l + 2) * 68 + q] = v.z;
            AsT[(k0l + 3) * 68 + q] = v.w;
        }
#pragma unroll
        for (int r = 0; r < 4; ++r) {
            int idx = tid + (r << 8);
            int kk = idx >> 4;
            int d0 = (idx & 15) << 2;
            float4 v = *reinterpret_cast<const float4*>(
                &V[((size_t)b * SS + (kc << 6) + kk) * ADIM + d0]);
            *reinterpret_cast<float4*>(&Vs[kk * 68 + d0]) = v;
        }
        __syncthreads();
#pragma unroll 16
        for (int kk = 0; kk < 64; ++kk) {
            float4 a  = *reinterpret_cast<const float4*>(&AsT[kk * 68 + (ty << 2)]);
            float4 vv = *reinterpret_cast<const float4*>(&Vs[kk * 68 + (tx << 2)]);
            const float aa[4] = {a.x, a.y, a.z, a.w};
            const float va[4] = {vv.x, vv.y, vv.z, vv.w};
#pragma unroll
            for (int i = 0; i < 4; ++i)
#pragma unroll
                for (int j = 0; j < 4; ++j)
                    t_acc[i][j] += aa[i] * va[j];
        }
    }
    __syncthreads();
#pragma unroll
    for (int i = 0; i < 4; ++i)
#pragma unroll
        for (int j = 0; j < 4; ++j)
            UsT[(tx << 2) + j][(ty << 2) + i] = t_acc[i][j];

    float o_acc[4][16];
#pragma unroll
    for (int i = 0; i < 4; ++i)
#pragma unroll
        for (int t = 0; t < 16; ++t) o_acc[i][t] = 0.f;

    for (int dc = 0; dc < 2; ++dc) {
        __syncthreads();
#pragma unroll
        for (int r = 0; r < 8; ++r) {
            int idx = tid + (r << 8);
            int dl = idx >> 6;
            int n0 = (idx & 63) << 2;
            float4 w = *reinterpret_cast<const float4*>(
                &Wh[((size_t)((dc << 5) + dl)) * HIDD + n0]);
            *reinterpret_cast<float4*>(&Whs[dl * 260 + n0]) = w;
        }
        __syncthreads();
#pragma unroll 8
        for (int dl = 0; dl < 32; ++dl) {
            float4 u = *reinterpret_cast<const float4*>(&UsT[(dc << 5) + dl][ty << 2]);
            const float ua[4] = {u.x, u.y, u.z, u.w};
#pragma unroll
            for (int jj = 0; jj < 4; ++jj) {
                float4 w = *reinterpret_cast<const float4*>(&Whs[dl * 260 + (jj << 6) + (tx << 2)]);
                const float wa[4] = {w.x, w.y, w.z, w.w};
#pragma unroll
                for (int i = 0; i < 4; ++i) {
                    o_acc[i][(jj << 2) + 0] += ua[i] * wa[0];
                    o_acc[i][(jj << 2) + 1] += ua[i] * wa[1];
                    o_acc[i][(jj << 2) + 2] += ua[i] * wa[2];
                    o_acc[i][(jj << 2) + 3] += ua[i] * wa[3];
                }
            }
        }
    }

#pragma unroll
    for (int i = 0; i < 4; ++i) {
        const int q = q0 + (ty << 2) + i;
#pragma unroll
        for (int jj = 0; jj < 4; ++jj) {
            const int n = (jj << 6) + (tx << 2);
            float4 bv4 = *reinterpret_cast<const float4*>(&bh[n]);
            float4 o;
            o.x = o_acc[i][(jj << 2) + 0] + bv4.x;
            o.y = o_acc[i][(jj << 2) + 1] + bv4.y;
            o.z = o_acc[i][(jj << 2) + 2] + bv4.z;
            o.w = o_acc[i][(jj << 2) + 3] + bv4.w;
            *reinterpret_cast<float4*>(&out[((size_t)b * SS + q) * HIDD + n]) = o;
        }
    }
}

// ---------------------------------------------------------------------------
extern "C" void kernel_launch(void* const* d_in, const int* in_sizes, int n_in,
                              void* d_out, int out_size, void* d_ws, size_t ws_size,
                              hipStream_t stream)
{
    const float* query = (const float*)d_in[0];
    const float* key   = (const float*)d_in[1];
    const float* value = (const float*)d_in[2];
    const int*   mask  = (const int*)d_in[3];
    const float* Wq = (const float*)d_in[4];
    const float* bq = (const float*)d_in[5];
    const float* Wk = (const float*)d_in[6];
    const float* bk = (const float*)d_in[7];
    const float* Wv = (const float*)d_in[8];
    const float* bv = (const float*)d_in[9];
    const float* Wh = (const float*)d_in[10];
    const float* bh = (const float*)d_in[11];

    float* out  = (float*)d_out;                       // [B,S,HID]
    float* attn = out + (size_t)NB * SS * HIDD;        // [B,S,S]

    const size_t BS = (size_t)NB * SS;
    short* Qhi = (short*)d_ws;                         // frag-tiled [b][h][t16][ks2][64][8]
    short* Qlo = Qhi + BS * HIDD;
    short* Khi = Qlo + BS * HIDD;
    short* Klo = Khi + BS * HIDD;
    float* Vp  = (float*)(Klo + BS * HIDD);            // [BS, ADIM] fp32

    // WT lives at the head of the attn output region; qkv_gemm consumes it
    // before attn_probs_mfma overwrites that region. 576*256*2 shorts = 590KB.
    short* WT_hi = (short*)attn;
    short* WT_lo = WT_hi + NTOT * HIDD;

    prep_weights<<<dim3(NTOT), 256, 0, stream>>>(Wq, Wk, Wv, WT_hi, WT_lo);
    qkv_gemm<<<dim3(512, 9), 256, 0, stream>>>(query, key, value, WT_hi, WT_lo,
                                               bq, bk, bv, Qhi, Qlo, Khi, Klo, Vp);
    attn_probs_mfma<<<dim3(1024), 256, 0, stream>>>(Qhi, Qlo, Khi, Klo, mask, attn);
    attn_out_kernel<<<dim3(64, 8), 256, 0, stream>>>(attn, Vp, Wh, bh, out);
}